// Round 6
// baseline (114.484 us; speedup 1.0000x reference)
//
#include <hip/hip_runtime.h>

#define NN    1024
#define INF   21
#define EE    128
#define NB    65   // 2*BINS+1
#define BINSV 32

typedef float f32x4 __attribute__((ext_vector_type(4)));

// Kernel 1 (merged prep): blocks [0, NN) do the two linear projections;
// blocks [NN, NN+NB) build ptab[d][e] = Wp[e][d] + bp[e].
__global__ __launch_bounds__(128) void prep_kernel(
    const float* __restrict__ tf,
    const float* __restrict__ Wa, const float* __restrict__ ba,
    const float* __restrict__ Wb, const float* __restrict__ bb,
    const float* __restrict__ Wp, const float* __restrict__ bp,
    float* __restrict__ a, float* __restrict__ b, float* __restrict__ ptab) {
  const int e = threadIdx.x;  // 0..127
  if (blockIdx.x < NN) {
    const int i = blockIdx.x;
    __shared__ float row[INF];
    if (e < INF) row[e] = tf[i * INF + e];
    __syncthreads();
    float sa = ba[e];
    float sb = bb[e];
#pragma unroll
    for (int k = 0; k < INF; ++k) {
      float r = row[k];
      sa = fmaf(r, Wa[e * INF + k], sa);
      sb = fmaf(r, Wb[e * INF + k], sb);
    }
    a[i * EE + e] = sa;
    b[i * EE + e] = sb;
  } else {
    const int d = blockIdx.x - NN;  // 0..64
    ptab[d * EE + e] = Wp[e * NB + d] + bp[e];
  }
}

// Kernel 2: out[i][j][e] = a[i][e] + b[j][e] + ptab[clip(ri_i-ri_j)][e]
// One block per row i. ROTATED j-sweep: block i starts at j=i, so at any
// instant the 1024 blocks read 1024 DIFFERENT b-lines (kills the L2
// same-line convoy). Stores stay 1KB-contiguous per wave.
__global__ __launch_bounds__(512) void fill_kernel(
    const float* __restrict__ a, const float* __restrict__ b,
    const float* __restrict__ ptab, const int* __restrict__ ri,
    float* __restrict__ out) {
  __shared__ int sri[NN];
  const int tid = threadIdx.x;
  for (int t = tid; t < NN; t += 512) sri[t] = ri[t];
  __syncthreads();

  const int i  = blockIdx.x;
  const int e4 = tid & 31;   // f32x4 index within E
  const int jg = tid >> 5;   // 0..15

  const f32x4* __restrict__ b4 = reinterpret_cast<const f32x4*>(b);
  const f32x4* __restrict__ p4 = reinterpret_cast<const f32x4*>(ptab);

  const f32x4 av = reinterpret_cast<const f32x4*>(a + i * EE)[e4];
  const int rii = sri[i];
  f32x4* outrow = reinterpret_cast<f32x4*>(out + (size_t)i * NN * EE);

  auto bin = [&](int j) {
    int d = rii - sri[j];
    d = (d < -BINSV) ? -BINSV : (d > BINSV ? BINSV : d);
    return d + BINSV;
  };

  // 1-deep pipeline on the global b-load; j rotated per block.
  int j = (i + jg) & (NN - 1);
  f32x4 bv = b4[j * 32 + e4];

  for (int t = 1; t < NN / 16; ++t) {
    const int jn = (i + jg + 16 * t) & (NN - 1);
    f32x4 bvn = b4[jn * 32 + e4];
    const f32x4 o = av + bv + p4[bin(j) * 32 + e4];
    __builtin_nontemporal_store(o, outrow + j * 32 + e4);
    j = jn; bv = bvn;
  }
  const f32x4 o = av + bv + p4[bin(j) * 32 + e4];
  __builtin_nontemporal_store(o, outrow + j * 32 + e4);
}

extern "C" void kernel_launch(void* const* d_in, const int* in_sizes, int n_in,
                              void* d_out, int out_size, void* d_ws, size_t ws_size,
                              hipStream_t stream) {
  const float* tf = (const float*)d_in[0];
  const int*   ri = (const int*)d_in[1];
  const float* Wa = (const float*)d_in[2];
  const float* ba = (const float*)d_in[3];
  const float* Wb = (const float*)d_in[4];
  const float* bb = (const float*)d_in[5];
  const float* Wp = (const float*)d_in[6];
  const float* bp = (const float*)d_in[7];
  float* out = (float*)d_out;

  float* ws   = (float*)d_ws;
  float* a    = ws;                 // N*E floats
  float* b    = ws + NN * EE;       // N*E floats
  float* ptab = ws + 2 * NN * EE;   // 65*E floats

  prep_kernel<<<NN + NB, 128, 0, stream>>>(tf, Wa, ba, Wb, bb, Wp, bp, a, b, ptab);
  fill_kernel<<<NN, 512, 0, stream>>>(a, b, ptab, ri, out);
}

// Round 7
// 110.844 us; speedup vs baseline: 1.0328x; 1.0328x over previous
//
#include <hip/hip_runtime.h>

#define NN    1024
#define INF   21
#define EE    128
#define NB    65   // 2*BINS+1
#define BINSV 32

typedef float f32x4 __attribute__((ext_vector_type(4)));

// Kernel 1 (merged prep): blocks [0, NN) do the two linear projections;
// blocks [NN, NN+NB) build ptab[d][e] = Wp[e][d] + bp[e].
__global__ __launch_bounds__(128) void prep_kernel(
    const float* __restrict__ tf,
    const float* __restrict__ Wa, const float* __restrict__ ba,
    const float* __restrict__ Wb, const float* __restrict__ bb,
    const float* __restrict__ Wp, const float* __restrict__ bp,
    float* __restrict__ a, float* __restrict__ b, float* __restrict__ ptab) {
  const int e = threadIdx.x;  // 0..127
  if (blockIdx.x < NN) {
    const int i = blockIdx.x;
    __shared__ float row[INF];
    if (e < INF) row[e] = tf[i * INF + e];
    __syncthreads();
    float sa = ba[e];
    float sb = bb[e];
#pragma unroll
    for (int k = 0; k < INF; ++k) {
      float r = row[k];
      sa = fmaf(r, Wa[e * INF + k], sa);
      sb = fmaf(r, Wb[e * INF + k], sb);
    }
    a[i * EE + e] = sa;
    b[i * EE + e] = sb;
  } else {
    const int d = blockIdx.x - NN;  // 0..64
    ptab[d * EE + e] = Wp[e * NB + d] + bp[e];
  }
}

// Kernel 2 (transposed sweep): global wave w owns a FIXED j-pair
// (jp = w & 511; j = 2*jp + half) and sweeps i = 16*t + (w>>9).
// At step t the whole device writes output units [t*8192, (t+1)*8192)
// = one contiguous 8 MB window marching linearly -> HBM row-buffer hits,
// same pattern as the 6.7 TB/s memset. b[j] is loop-invariant (register).
__global__ __launch_bounds__(512) void fill_kernel(
    const float* __restrict__ a, const float* __restrict__ b,
    const float* __restrict__ ptab, const int* __restrict__ ri,
    float* __restrict__ out) {
  __shared__ int sri[NN];
  const int tid = threadIdx.x;
  for (int t = tid; t < NN; t += 512) sri[t] = ri[t];
  __syncthreads();

  const int lane = tid & 63;
  const int hi   = lane >> 5;          // half-wave: 0 or 1
  const int e4   = lane & 31;          // f32x4 index within E
  const int w    = blockIdx.x * 8 + (tid >> 6);  // global wave 0..8191
  const int jp   = w & 511;
  const int ic   = w >> 9;             // 0..15
  const int j    = 2 * jp + hi;

  const f32x4* __restrict__ a4 = reinterpret_cast<const f32x4*>(a);
  const f32x4* __restrict__ p4 = reinterpret_cast<const f32x4*>(ptab);

  // loop-invariant operand: b row for this lane's j
  const f32x4 bv = reinterpret_cast<const f32x4*>(b + j * EE)[e4];
  const int rj = sri[j];

  f32x4* __restrict__ o4 = reinterpret_cast<f32x4*>(out);

#pragma unroll 4
  for (int t = 0; t < 64; ++t) {
    const int i = t * 16 + ic;
    const f32x4 av = a4[i * 32 + e4];
    int d = sri[i] - rj;
    d = min(max(d, -BINSV), BINSV) + BINSV;
    const f32x4 pv = p4[d * 32 + e4];
    const f32x4 o = av + bv + pv;
    // unit u = t*8192 + w is 1 KB (64 f32x4); lane writes u*64 + hi*32 + e4
    const size_t u = (size_t)t * 8192 + w;
    __builtin_nontemporal_store(o, o4 + u * 64 + hi * 32 + e4);
  }
}

extern "C" void kernel_launch(void* const* d_in, const int* in_sizes, int n_in,
                              void* d_out, int out_size, void* d_ws, size_t ws_size,
                              hipStream_t stream) {
  const float* tf = (const float*)d_in[0];
  const int*   ri = (const int*)d_in[1];
  const float* Wa = (const float*)d_in[2];
  const float* ba = (const float*)d_in[3];
  const float* Wb = (const float*)d_in[4];
  const float* bb = (const float*)d_in[5];
  const float* Wp = (const float*)d_in[6];
  const float* bp = (const float*)d_in[7];
  float* out = (float*)d_out;

  float* ws   = (float*)d_ws;
  float* a    = ws;                 // N*E floats
  float* b    = ws + NN * EE;       // N*E floats
  float* ptab = ws + 2 * NN * EE;   // 65*E floats

  prep_kernel<<<NN + NB, 128, 0, stream>>>(tf, Wa, ba, Wb, bb, Wp, bp, a, b, ptab);
  fill_kernel<<<NN, 512, 0, stream>>>(a, b, ptab, ri, out);
}